// Round 7
// baseline (249.102 us; speedup 1.0000x reference)
//
#include <hip/hip_runtime.h>

typedef __attribute__((ext_vector_type(8))) short s16x8;   // 8 bf16
typedef __attribute__((ext_vector_type(4))) float f32x4;
typedef __attribute__((ext_vector_type(4))) int   i32x4;

#define HID 512
#define NROWS 8192
#define TAU_INV 1.25f
#define LOG2E 1.4426950408889634f

// counted waits (T4). memory clobber: LDS/VMEM ops may not cross.
#define VMCNT(n)  asm volatile("s_waitcnt vmcnt(" #n ")" ::: "memory")
#define LGKMCNT0  asm volatile("s_waitcnt lgkmcnt(0)" ::: "memory")

__device__ __forceinline__ float bf2f(short s) {
    union { unsigned u; float f; } v;
    v.u = ((unsigned)(unsigned short)s) << 16;
    return v.f;
}
__device__ __forceinline__ short f2bf(float f) {
    unsigned u = __float_as_uint(f);
    u += 0x7fffu + ((u >> 16) & 1u);   // round-to-nearest-even
    return (short)(u >> 16);
}

__device__ __forceinline__ void gload_lds16(const void* g, void* l) {
    __builtin_amdgcn_global_load_lds(
        (const __attribute__((address_space(1))) unsigned int*)g,
        (__attribute__((address_space(3))) unsigned int*)l, 16, 0, 0);
}

__device__ __forceinline__ int dot4i(int a, int b) {
    int s = 0;
#pragma unroll
    for (int i = 0; i < 4; ++i)
        s += (int)(signed char)(a >> (8 * i)) * (int)(signed char)(b >> (8 * i));
    return s;
}

// ---------------------------------------------------------------------------
// Fused fp32->bf16 convert for z_mp, z_sc, W1, W2 + zeroing of rowsum/colsum
// (tail blocks), all in one launch.  (R1-verified)
// ---------------------------------------------------------------------------
__global__ void convert_all(const float* __restrict__ z1, const float* __restrict__ z2,
                            const float* __restrict__ w1, const float* __restrict__ w2,
                            short* __restrict__ Zb1, short* __restrict__ Zb2,
                            short* __restrict__ Wb1, short* __restrict__ Wb2,
                            float* __restrict__ zsum)
{
    const int ZN = NROWS * HID, WN = HID * HID;
    const int NCONV = (2 * ZN + 2 * WN) / 1024;   // conversion blocks
    if ((int)blockIdx.x >= NCONV) {               // tail: zero rowsum+colsum
        int zi = ((int)blockIdx.x - NCONV) * 1024 + threadIdx.x * 4;
        if (zi < 2 * NROWS)
            *(float4*)(zsum + zi) = make_float4(0.f, 0.f, 0.f, 0.f);
        return;
    }
    long i = (long)(blockIdx.x * blockDim.x + threadIdx.x) * 4;
    const float* src;
    short* dst;
    long off;
    if (i < ZN)                { src = z1; dst = Zb1; off = i; }
    else if (i < 2L * ZN)      { src = z2; dst = Zb2; off = i - ZN; }
    else if (i < 2L * ZN + WN) { src = w1; dst = Wb1; off = i - 2L * ZN; }
    else                       { src = w2; dst = Wb2; off = i - 2L * ZN - WN; }
    float4 v = *(const float4*)(src + off);
    short4 o;
    o.x = f2bf(v.x); o.y = f2bf(v.y); o.z = f2bf(v.z); o.w = f2bf(v.w);
    *(short4*)(dst + off) = o;
}

// ---------------------------------------------------------------------------
// bf16 NT GEMM, 64x128 tile, double-buffered LDS staging — R1-verified best
// (stage k+1 -> ds_read k -> MFMA -> one __syncthreads per iter). Untouched.
// ---------------------------------------------------------------------------
__global__ __launch_bounds__(256, 4)
void gemm_proj(const short* __restrict__ A0, const short* __restrict__ A1,
               const short* __restrict__ B, const float* __restrict__ bias,
               short* __restrict__ C0, short* __restrict__ C1, int do_elu)
{
    __shared__ short ldsA[2][64 * 32];    // 2 x 4 KB
    __shared__ short ldsB[2][128 * 32];   // 2 x 8 KB
    const short* A = blockIdx.z ? A1 : A0;
    short* C = blockIdx.z ? C1 : C0;
    const int tid = threadIdx.x;
    const int w = tid >> 6, lane = tid & 63;
    const int wm = w & 1, wn = w >> 1;
    const int quad = lane >> 4, r16 = lane & 15;
    const int bM = blockIdx.x * 64, bN = blockIdx.y * 128;
    const int lrow = lane >> 2;
    const int lq   = ((lane & 3) ^ ((lane >> 3) & 3)) * 8;   // swizzled src slot (shorts)
    const int aswz = (quad ^ ((r16 >> 1) & 3)) * 8;          // swizzled read slot (shorts)

    auto stage = [&](int k0, int bufi) {
        {   // A: 4 chunks of 16 rows, one per wave
            int r0 = w * 16;
            gload_lds16(A + (size_t)(bM + r0 + lrow) * HID + k0 + lq, &ldsA[bufi][r0 * 32]);
        }
#pragma unroll
        for (int i = 0; i < 2; ++i) {   // B: 8 chunks, two per wave
            int r0 = (w * 2 + i) * 16;
            gload_lds16(B + (size_t)(bN + r0 + lrow) * HID + k0 + lq, &ldsB[bufi][r0 * 32]);
        }
    };

    f32x4 acc[2][4] = {};

    stage(0, 0);
    __syncthreads();                      // prologue loads resident

    int cur = 0;
#pragma unroll
    for (int k0 = 0; k0 < HID; k0 += 32) {
        if (k0 + 32 < HID) stage(k0 + 32, cur ^ 1);   // prefetch next K-tile
        s16x8 af[2], bfr[4];
#pragma unroll
        for (int t = 0; t < 2; ++t)
            af[t]  = *(const s16x8*)&ldsA[cur][(wm * 32 + t * 16 + r16) * 32 + aswz];
#pragma unroll
        for (int t = 0; t < 4; ++t)
            bfr[t] = *(const s16x8*)&ldsB[cur][(wn * 64 + t * 16 + r16) * 32 + aswz];
#pragma unroll
        for (int tm = 0; tm < 2; ++tm)
#pragma unroll
            for (int tn = 0; tn < 4; ++tn)
                acc[tm][tn] = __builtin_amdgcn_mfma_f32_16x16x32_bf16(
                    af[tm], bfr[tn], acc[tm][tn], 0, 0, 0);
        __syncthreads();                  // drains vmcnt AFTER compute cover
        cur ^= 1;
    }

#pragma unroll
    for (int tn = 0; tn < 4; ++tn) {
        int gcol = bN + wn * 64 + tn * 16 + r16;
        float bv = bias[gcol];
#pragma unroll
        for (int tm = 0; tm < 2; ++tm) {
#pragma unroll
            for (int r = 0; r < 4; ++r) {
                int grow = bM + wm * 32 + tm * 16 + quad * 4 + r;  // C/D: row=(lane>>4)*4+reg
                float v = acc[tm][tn][r] + bv;
                if (do_elu) v = v > 0.f ? v : __expf(v) - 1.f;
                C[(size_t)grow * HID + gcol] = f2bf(v);
            }
        }
    }
}

// ---------------------------------------------------------------------------
// normalize + int8 row-quantize: q = round(n * 127/max|n_row|), one wave/row.
// recip[row] = max|n_row|/127, so dot_real = i32acc * recip[r] * recip[c].
// ---------------------------------------------------------------------------
__global__ void normalize_quant(const short* __restrict__ P, char* __restrict__ Q,
                                float* __restrict__ recip, int nrows)
{
    int gt = blockIdx.x * blockDim.x + threadIdx.x;
    int row = gt >> 6, lane = gt & 63;
    if (row >= nrows) return;
    const short* p = P + (size_t)row * HID + lane * 8;
    s16x8 v = *(const s16x8*)p;
    float f[8], ss = 0.f, am = 0.f;
#pragma unroll
    for (int i = 0; i < 8; ++i) {
        f[i] = bf2f(v[i]);
        ss += f[i] * f[i];
        am = fmaxf(am, fabsf(f[i]));
    }
#pragma unroll
    for (int m = 1; m < 64; m <<= 1) {
        ss += __shfl_xor(ss, m, 64);
        am = fmaxf(am, __shfl_xor(am, m, 64));
    }
    float inv = rsqrtf(ss);
    float maxn = am * inv;             // max |n_i| over the row
    float s = 127.f / maxn;
    int lo = 0, hi = 0;
#pragma unroll
    for (int i = 0; i < 4; ++i) {
        int q0 = (int)lrintf(f[i] * inv * s);
        int q1 = (int)lrintf(f[i + 4] * inv * s);
        lo |= (q0 & 255) << (8 * i);
        hi |= (q1 & 255) << (8 * i);
    }
    ((int2*)(Q + (size_t)row * HID))[lane] = make_int2(lo, hi);
    if (lane == 0) recip[row] = maxn * (1.f / 127.f);
}

// ---------------------------------------------------------------------------
// int8 similarity — T3+T4 port: 256x256 tile, 8 waves (512 thr), BK=64,
// THREE LDS buffers (96 KB; tile-granular rotation -> no intra-tile buffer
// aliasing), counted vmcnt with 2 K-tiles in flight, ONE barrier per K-tile,
// fine per-phase interleave {stage 1 chunk of kt+2 | ds_read | 8 MFMA}.
// Hazards: RAW: kt's 4 loads are each wave's oldest -> VMCNT(4)+barrier
// proves landed for all waves (never drain to 0 mid-loop). WAR: buffer
// (kt+2)%3 was last ds_read during kt-1; LGKMCNT0+barrier at kt's top proves
// all waves' reads complete before any kt+2 write. XOR swizzle (R1-verified
// involution) on both stage-source and read side. Epilogue = R1 atomics
// (R6 proved partial-stores amplify writes 13x).
// ---------------------------------------------------------------------------
__global__ __launch_bounds__(512, 2)
void gemm_sim(const char* __restrict__ Q1, const char* __restrict__ Q2,
              const float* __restrict__ recip,
              float* __restrict__ rowsum, float* __restrict__ colsum)
{
    __shared__ char ldsA[3][256 * 64];   // 3 x 16 KB
    __shared__ char ldsB[3][256 * 64];   // 3 x 16 KB
    const int tid = threadIdx.x;
    const int w = tid >> 6, lane = tid & 63;
    const int wm = w >> 2, wn = w & 3;           // 2x4 wave grid -> 128x64 C per wave
    const int quad = lane >> 4, r16 = lane & 15;
    const int bM = blockIdx.x * 256, bN = blockIdx.y * 256;
    const int lrow = lane >> 2;
    const int lq   = ((lane & 3) ^ ((lane >> 3) & 3)) * 16;  // swizzled src slot (bytes)
    const int aswz = (quad ^ ((r16 >> 1) & 3)) * 16;         // swizzled read slot (bytes)

    // one 128-row (8 KB) chunk of a K-tile: exactly 1 vmem instr per wave
    auto stageA = [&](int kt, int sb, int r0) {
        gload_lds16(Q1 + (size_t)(bM + r0 + w * 16 + lrow) * HID + kt * 64 + lq,
                    &ldsA[sb][(r0 + w * 16) * 64]);
    };
    auto stageB = [&](int kt, int sb, int r0) {
        gload_lds16(Q2 + (size_t)(bN + r0 + w * 16 + lrow) * HID + kt * 64 + lq,
                    &ldsB[sb][(r0 + w * 16) * 64]);
    };

    i32x4 acc[8][4] = {};

    // prologue: 2 K-tiles in flight (8 vmem instr per wave)
    stageA(0, 0, 0); stageA(0, 0, 128); stageB(0, 0, 0); stageB(0, 0, 128);
    stageA(1, 1, 0); stageA(1, 1, 128); stageB(1, 1, 0); stageB(1, 1, 128);

    const int NT = HID / 64;   // 8 K-tiles
#pragma unroll
    for (int kt = 0; kt < NT; ++kt) {
        const int rb = kt % 3, sb = (kt + 2) % 3;
        LGKMCNT0;                                   // WAR: my kt-1 ds_reads complete
        if (kt < NT - 1) VMCNT(4); else VMCNT(0);   // RAW: kt landed, kt+1 in flight
        __builtin_amdgcn_s_barrier();

        i32x4 bfr[4];
        // per-phase body: 2 A-frag ds_reads + 8 MFMA on acc rows tm0,tm0+1
        auto phase = [&](int tm0) {
            i32x4 a0 = *(const i32x4*)&ldsA[rb][(wm * 128 + tm0 * 16 + r16) * 64 + aswz];
            i32x4 a1 = *(const i32x4*)&ldsA[rb][(wm * 128 + (tm0 + 1) * 16 + r16) * 64 + aswz];
            __builtin_amdgcn_s_setprio(1);
#pragma unroll
            for (int tn = 0; tn < 4; ++tn) {
                acc[tm0][tn]     = __builtin_amdgcn_mfma_i32_16x16x64_i8(
                    a0, bfr[tn], acc[tm0][tn], 0, 0, 0);
                acc[tm0 + 1][tn] = __builtin_amdgcn_mfma_i32_16x16x64_i8(
                    a1, bfr[tn], acc[tm0 + 1][tn], 0, 0, 0);
            }
            __builtin_amdgcn_s_setprio(0);
        };

        // phase 0: stage A chunk 0 of kt+2 | B frags + A frags 0,1 | MFMA
        if (kt < NT - 2) stageA(kt + 2, sb, 0);
#pragma unroll
        for (int tn = 0; tn < 4; ++tn)
            bfr[tn] = *(const i32x4*)&ldsB[rb][(wn * 64 + tn * 16 + r16) * 64 + aswz];
        phase(0);
        // phase 1: stage A chunk 1 | A frags 2,3 | MFMA
        if (kt < NT - 2) stageA(kt + 2, sb, 128);
        phase(2);
        // phase 2: stage B chunk 0 | A frags 4,5 | MFMA
        if (kt < NT - 2) stageB(kt + 2, sb, 0);
        phase(4);
        // phase 3: stage B chunk 1 | A frags 6,7 | MFMA
        if (kt < NT - 2) stageB(kt + 2, sb, 128);
        phase(6);
    }

    // epilogue: e = exp2(i32 * ra * cb); cb folds recip_col * TAU_INV * LOG2E
    float cb[4], cs[4] = {0.f, 0.f, 0.f, 0.f};
#pragma unroll
    for (int tn = 0; tn < 4; ++tn)
        cb[tn] = recip[NROWS + bN + wn * 64 + tn * 16 + r16] * (TAU_INV * LOG2E);

#pragma unroll
    for (int tm = 0; tm < 8; ++tm) {
#pragma unroll
        for (int r = 0; r < 4; ++r) {
            int grow = bM + wm * 128 + tm * 16 + quad * 4 + r;  // C/D: row=quad*4+reg
            float ra = recip[grow];
            float rs = 0.f;
#pragma unroll
            for (int tn = 0; tn < 4; ++tn) {
                float e = exp2f((float)acc[tm][tn][r] * ra * cb[tn]);
                rs += e;
                cs[tn] += e;
            }
#pragma unroll
            for (int m = 1; m < 16; m <<= 1) rs += __shfl_xor(rs, m, 64);
            if (r16 == 0) atomicAdd(&rowsum[grow], rs);
        }
    }
#pragma unroll
    for (int tn = 0; tn < 4; ++tn) {
        float c = cs[tn];
        c += __shfl_xor(c, 16, 64);
        c += __shfl_xor(c, 32, 64);
        if (quad == 0)
            atomicAdd(&colsum[bN + wn * 64 + tn * 16 + r16], c);
    }
}

// ---------------------------------------------------------------------------
// Edge numerators, one wave per node (edges are row-sorted, 8 per node):
// row fragments loaded once; exact int8 dots in float; direct store (no atomic).
// ---------------------------------------------------------------------------
__global__ void edge_kernel(const char* __restrict__ Q1, const char* __restrict__ Q2,
                            const float* __restrict__ recip, const int* __restrict__ pos,
                            float* __restrict__ smp, float* __restrict__ ssc, int E)
{
    int row = blockIdx.x * (blockDim.x >> 6) + (threadIdx.x >> 6);
    int lane = threadIdx.x & 63;
    if (row >= NROWS) return;
    int2 a1 = ((const int2*)(Q1 + (size_t)row * HID))[lane];
    int2 a2 = ((const int2*)(Q2 + (size_t)row * HID))[lane];
    float s1 = 0.f, s2 = 0.f;
    float ir1 = recip[row], ir2 = recip[NROWS + row];
#pragma unroll
    for (int e = 0; e < 8; ++e) {
        int c = pos[E + row * 8 + e];
        int2 b2 = ((const int2*)(Q2 + (size_t)c * HID))[lane];
        int2 b1 = ((const int2*)(Q1 + (size_t)c * HID))[lane];
        float d1 = (float)(dot4i(a1.x, b2.x) + dot4i(a1.y, b2.y));
        float d2 = (float)(dot4i(b1.x, a2.x) + dot4i(b1.y, a2.y));
#pragma unroll
        for (int m = 1; m < 64; m <<= 1) {
            d1 += __shfl_xor(d1, m, 64);
            d2 += __shfl_xor(d2, m, 64);
        }
        if (lane == 0) {
            s1 += __expf(d1 * ir1 * recip[NROWS + c] * TAU_INV);   // S[row,c]
            s2 += __expf(d2 * recip[c] * ir2 * TAU_INV);           // S[c,row]
        }
    }
    if (lane == 0) { smp[row] = s1; ssc[row] = s2; }
}

// Single-block finalize (1024 threads): loss = mean over rows -> out[0].
__global__ void finalize(const float* __restrict__ rowsum, const float* __restrict__ colsum,
                         const float* __restrict__ smp, const float* __restrict__ ssc,
                         float* __restrict__ out, int n)
{
    float contrib = 0.f;
    for (int i = threadIdx.x; i < n; i += blockDim.x) {
        float t = (smp[i] / rowsum[i]) * (ssc[i] / colsum[i]);
        contrib += -0.5f * logf(t) / (float)n;
    }
#pragma unroll
    for (int m = 1; m < 64; m <<= 1) contrib += __shfl_xor(contrib, m, 64);
    __shared__ float wsum[16];
    int w = threadIdx.x >> 6, lane = threadIdx.x & 63;
    if (lane == 0) wsum[w] = contrib;
    __syncthreads();
    if (threadIdx.x == 0) {
        float s = 0.f;
#pragma unroll
        for (int i = 0; i < 16; ++i) s += wsum[i];
        out[0] = s;
    }
}

extern "C" void kernel_launch(void* const* d_in, const int* in_sizes, int n_in,
                              void* d_out, int out_size, void* d_ws, size_t ws_size,
                              hipStream_t stream)
{
    const float* z_mp = (const float*)d_in[0];
    const float* z_sc = (const float*)d_in[1];
    const float* W1f  = (const float*)d_in[2];
    const float* b1   = (const float*)d_in[3];
    const float* W2f  = (const float*)d_in[4];
    const float* b2   = (const float*)d_in[5];
    const int*   pos  = (const int*)d_in[6];
    const int E = in_sizes[6] / 2;
    const int ZN = NROWS * HID;       // 4M elems
    const int WN = HID * HID;         // 256K elems

    // workspace layout (~34 MB):
    //   [0,16MB)   : Zb_mp, Zb_sc (bf16) -> dead after proj1 -> reused as P1,P2
    //   [16,32MB)  : H1,H2 (bf16) -> dead after proj2 -> reused as Q (int8, 8MB)
    //   [32MB,..)  : Wb1, Wb2, rowsum, colsum, recip(64KB), smp, ssc
    char* ws = (char*)d_ws;
    short* Zb1 = (short*)ws;
    short* Zb2 = Zb1 + ZN;
    short* P1  = Zb1;                 // alias: Zb dead after proj1
    short* P2  = Zb2;
    short* H1  = (short*)(ws + (size_t)16 * 1024 * 1024);
    short* H2  = H1 + ZN;
    char*  Q   = (char*)H1;           // alias: H dead after proj2; 2*NROWS rows
    char*  Q1  = Q;
    char*  Q2  = Q + (size_t)NROWS * HID;
    short* Wb1 = (short*)(ws + (size_t)32 * 1024 * 1024);
    short* Wb2 = Wb1 + WN;
    float* rowsum = (float*)(Wb2 + WN);
    float* colsum = rowsum + NROWS;
    float* recip  = colsum + NROWS;   // 2*NROWS floats
    float* smp    = recip + 2 * NROWS;
    float* ssc    = smp + NROWS;

    dim3 blk(256);
    // fp32 -> bf16 conversions + rowsum/colsum zeroing (single launch)
    convert_all<<<dim3((2 * ZN + 2 * WN) / 1024 + 16), blk, 0, stream>>>(
        z_mp, z_sc, W1f, W2f, Zb1, Zb2, Wb1, Wb2, rowsum);
    // H = elu(Z @ W1^T + b1) for both inputs (grid.z); 64x128 tiles, 1024 blocks
    gemm_proj<<<dim3(128, 4, 2), blk, 0, stream>>>(Zb1, Zb2, Wb1, b1, H1, H2, 1);
    // P = H @ W2^T + b2   (P overwrites Zb region — Zb dead now)
    gemm_proj<<<dim3(128, 4, 2), blk, 0, stream>>>(H1, H2, Wb2, b2, P1, P2, 0);
    // normalize + int8 quantize both P1,P2 (2*NROWS contiguous rows) -> Q, recip
    normalize_quant<<<dim3((2 * NROWS) / 4), blk, 0, stream>>>(P1, Q, recip, 2 * NROWS);
    // rowsum/colsum via i8 MFMA, 256x256 tiles, counted-vmcnt 4-phase pipeline
    gemm_sim<<<dim3(32, 32), dim3(512), 0, stream>>>(Q1, Q2, recip, rowsum, colsum);
    // per-edge numerators, one wave per node, direct store
    edge_kernel<<<dim3(NROWS / 4), blk, 0, stream>>>(Q1, Q2, recip, pos, smp, ssc, E);
    // single-block reduce straight into d_out
    finalize<<<dim3(1), dim3(1024), 0, stream>>>(rowsum, colsum, smp, ssc, (float*)d_out, NROWS);
}

// Round 8
// 219.831 us; speedup vs baseline: 1.1331x; 1.1331x over previous
//
#include <hip/hip_runtime.h>

typedef __attribute__((ext_vector_type(8))) short s16x8;   // 8 bf16
typedef __attribute__((ext_vector_type(4))) float f32x4;
typedef __attribute__((ext_vector_type(4))) int   i32x4;

#define HID 512
#define NROWS 8192
#define TAU_INV 1.25f
#define LOG2E 1.4426950408889634f

// counted waits + raw barrier (T3/T4). memory clobber: LDS/VMEM may not cross.
#define VMCNT(n)  asm volatile("s_waitcnt vmcnt(" #n ")" ::: "memory")
#define LGKMCNT0  asm volatile("s_waitcnt lgkmcnt(0)" ::: "memory")
#define BARRIER   asm volatile("s_barrier" ::: "memory")

__device__ __forceinline__ float bf2f(short s) {
    union { unsigned u; float f; } v;
    v.u = ((unsigned)(unsigned short)s) << 16;
    return v.f;
}
__device__ __forceinline__ short f2bf(float f) {
    unsigned u = __float_as_uint(f);
    u += 0x7fffu + ((u >> 16) & 1u);   // round-to-nearest-even
    return (short)(u >> 16);
}

__device__ __forceinline__ void gload_lds16(const void* g, void* l) {
    __builtin_amdgcn_global_load_lds(
        (const __attribute__((address_space(1))) unsigned int*)g,
        (__attribute__((address_space(3))) unsigned int*)l, 16, 0, 0);
}

__device__ __forceinline__ int dot4i(int a, int b) {
    int s = 0;
#pragma unroll
    for (int i = 0; i < 4; ++i)
        s += (int)(signed char)(a >> (8 * i)) * (int)(signed char)(b >> (8 * i));
    return s;
}

// ---------------------------------------------------------------------------
// Fused fp32->bf16 convert for z_mp, z_sc, W1, W2 + zeroing of rowsum/colsum
// (tail blocks), all in one launch.  (R1-verified)
// ---------------------------------------------------------------------------
__global__ void convert_all(const float* __restrict__ z1, const float* __restrict__ z2,
                            const float* __restrict__ w1, const float* __restrict__ w2,
                            short* __restrict__ Zb1, short* __restrict__ Zb2,
                            short* __restrict__ Wb1, short* __restrict__ Wb2,
                            float* __restrict__ zsum)
{
    const int ZN = NROWS * HID, WN = HID * HID;
    const int NCONV = (2 * ZN + 2 * WN) / 1024;   // conversion blocks
    if ((int)blockIdx.x >= NCONV) {               // tail: zero rowsum+colsum
        int zi = ((int)blockIdx.x - NCONV) * 1024 + threadIdx.x * 4;
        if (zi < 2 * NROWS)
            *(float4*)(zsum + zi) = make_float4(0.f, 0.f, 0.f, 0.f);
        return;
    }
    long i = (long)(blockIdx.x * blockDim.x + threadIdx.x) * 4;
    const float* src;
    short* dst;
    long off;
    if (i < ZN)                { src = z1; dst = Zb1; off = i; }
    else if (i < 2L * ZN)      { src = z2; dst = Zb2; off = i - ZN; }
    else if (i < 2L * ZN + WN) { src = w1; dst = Wb1; off = i - 2L * ZN; }
    else                       { src = w2; dst = Wb2; off = i - 2L * ZN - WN; }
    float4 v = *(const float4*)(src + off);
    short4 o;
    o.x = f2bf(v.x); o.y = f2bf(v.y); o.z = f2bf(v.z); o.w = f2bf(v.w);
    *(short4*)(dst + off) = o;
}

// ---------------------------------------------------------------------------
// bf16 NT GEMM, 64x128 tile, double-buffered LDS staging — R1-verified best
// (stage k+1 -> ds_read k -> MFMA -> one __syncthreads per iter). Untouched.
// ---------------------------------------------------------------------------
__global__ __launch_bounds__(256, 4)
void gemm_proj(const short* __restrict__ A0, const short* __restrict__ A1,
               const short* __restrict__ B, const float* __restrict__ bias,
               short* __restrict__ C0, short* __restrict__ C1, int do_elu)
{
    __shared__ short ldsA[2][64 * 32];    // 2 x 4 KB
    __shared__ short ldsB[2][128 * 32];   // 2 x 8 KB
    const short* A = blockIdx.z ? A1 : A0;
    short* C = blockIdx.z ? C1 : C0;
    const int tid = threadIdx.x;
    const int w = tid >> 6, lane = tid & 63;
    const int wm = w & 1, wn = w >> 1;
    const int quad = lane >> 4, r16 = lane & 15;
    const int bM = blockIdx.x * 64, bN = blockIdx.y * 128;
    const int lrow = lane >> 2;
    const int lq   = ((lane & 3) ^ ((lane >> 3) & 3)) * 8;   // swizzled src slot (shorts)
    const int aswz = (quad ^ ((r16 >> 1) & 3)) * 8;          // swizzled read slot (shorts)

    auto stage = [&](int k0, int bufi) {
        {   // A: 4 chunks of 16 rows, one per wave
            int r0 = w * 16;
            gload_lds16(A + (size_t)(bM + r0 + lrow) * HID + k0 + lq, &ldsA[bufi][r0 * 32]);
        }
#pragma unroll
        for (int i = 0; i < 2; ++i) {   // B: 8 chunks, two per wave
            int r0 = (w * 2 + i) * 16;
            gload_lds16(B + (size_t)(bN + r0 + lrow) * HID + k0 + lq, &ldsB[bufi][r0 * 32]);
        }
    };

    f32x4 acc[2][4] = {};

    stage(0, 0);
    __syncthreads();                      // prologue loads resident

    int cur = 0;
#pragma unroll
    for (int k0 = 0; k0 < HID; k0 += 32) {
        if (k0 + 32 < HID) stage(k0 + 32, cur ^ 1);   // prefetch next K-tile
        s16x8 af[2], bfr[4];
#pragma unroll
        for (int t = 0; t < 2; ++t)
            af[t]  = *(const s16x8*)&ldsA[cur][(wm * 32 + t * 16 + r16) * 32 + aswz];
#pragma unroll
        for (int t = 0; t < 4; ++t)
            bfr[t] = *(const s16x8*)&ldsB[cur][(wn * 64 + t * 16 + r16) * 32 + aswz];
#pragma unroll
        for (int tm = 0; tm < 2; ++tm)
#pragma unroll
            for (int tn = 0; tn < 4; ++tn)
                acc[tm][tn] = __builtin_amdgcn_mfma_f32_16x16x32_bf16(
                    af[tm], bfr[tn], acc[tm][tn], 0, 0, 0);
        __syncthreads();                  // drains vmcnt AFTER compute cover
        cur ^= 1;
    }

#pragma unroll
    for (int tn = 0; tn < 4; ++tn) {
        int gcol = bN + wn * 64 + tn * 16 + r16;
        float bv = bias[gcol];
#pragma unroll
        for (int tm = 0; tm < 2; ++tm) {
#pragma unroll
            for (int r = 0; r < 4; ++r) {
                int grow = bM + wm * 32 + tm * 16 + quad * 4 + r;  // C/D: row=(lane>>4)*4+reg
                float v = acc[tm][tn][r] + bv;
                if (do_elu) v = v > 0.f ? v : __expf(v) - 1.f;
                C[(size_t)grow * HID + gcol] = f2bf(v);
            }
        }
    }
}

// ---------------------------------------------------------------------------
// normalize + int8 row-quantize: q = round(n * 127/max|n_row|), one wave/row.
// recip[row] = max|n_row|/127, so dot_real = i32acc * recip[r] * recip[c].
// ---------------------------------------------------------------------------
__global__ void normalize_quant(const short* __restrict__ P, char* __restrict__ Q,
                                float* __restrict__ recip, int nrows)
{
    int gt = blockIdx.x * blockDim.x + threadIdx.x;
    int row = gt >> 6, lane = gt & 63;
    if (row >= nrows) return;
    const short* p = P + (size_t)row * HID + lane * 8;
    s16x8 v = *(const s16x8*)p;
    float f[8], ss = 0.f, am = 0.f;
#pragma unroll
    for (int i = 0; i < 8; ++i) {
        f[i] = bf2f(v[i]);
        ss += f[i] * f[i];
        am = fmaxf(am, fabsf(f[i]));
    }
#pragma unroll
    for (int m = 1; m < 64; m <<= 1) {
        ss += __shfl_xor(ss, m, 64);
        am = fmaxf(am, __shfl_xor(am, m, 64));
    }
    float inv = rsqrtf(ss);
    float maxn = am * inv;             // max |n_i| over the row
    float s = 127.f / maxn;
    int lo = 0, hi = 0;
#pragma unroll
    for (int i = 0; i < 4; ++i) {
        int q0 = (int)lrintf(f[i] * inv * s);
        int q1 = (int)lrintf(f[i + 4] * inv * s);
        lo |= (q0 & 255) << (8 * i);
        hi |= (q1 & 255) << (8 * i);
    }
    ((int2*)(Q + (size_t)row * HID))[lane] = make_int2(lo, hi);
    if (lane == 0) recip[row] = maxn * (1.f / 127.f);
}

// ---------------------------------------------------------------------------
// int8 similarity — FAITHFUL 8-phase template (T3+T4+T5): 256x256 tile,
// 8 waves (512 thr), BK=64, 3 LDS buffers (96 KB), 1 block/CU (the reference
// template also runs 1 block/CU). Per K-tile: top {vmcnt(4) counted, never 0
// mid-loop; s_barrier} then FOUR phases, each
//   {ds_read frags -> stage 1 chunk of kt+2 -> s_barrier -> lgkmcnt(0)
//    -> setprio(1) 8 MFMA setprio(0) -> s_barrier}
// The barrier PAIRS around each MFMA cluster create the wave role-split that
// R7 (single barrier/K-tile) lacked. Hazards: RAW: my 4 oldest vmem = kt's
// chunks (vmcnt(4)); other waves' chunks guaranteed by their vmcnt(4) before
// the top barrier; ds_reads only after it. WAR: buffer (kt+2)%3 was last
// ds_read in iter kt-1, and every phase's lgkmcnt(0) precedes its closing
// barrier, so all reads complete before iter kt's stages can land.
// Epilogue: LDS-first reduction (ds_add_f32), then ONE global atomic per
// output element per block (global atomics 2.1M -> 0.5M; R7 showed fewer
// atomic sources -> less write amplification).
// ---------------------------------------------------------------------------
__global__ __launch_bounds__(512, 1)
void gemm_sim(const char* __restrict__ Q1, const char* __restrict__ Q2,
              const float* __restrict__ recip,
              float* __restrict__ rowsum, float* __restrict__ colsum)
{
    __shared__ char  ldsA[3][256 * 64];   // 3 x 16 KB
    __shared__ char  ldsB[3][256 * 64];   // 3 x 16 KB
    __shared__ float red[512];            // 256 row + 256 col partials
    const int tid = threadIdx.x;
    const int w = tid >> 6, lane = tid & 63;
    const int wm = w >> 2, wn = w & 3;           // 2x4 wave grid -> 128x64 C per wave
    const int quad = lane >> 4, r16 = lane & 15;
    const int bM = blockIdx.x * 256, bN = blockIdx.y * 256;
    const int lrow = lane >> 2;
    const int lq   = ((lane & 3) ^ ((lane >> 3) & 3)) * 16;  // swizzled src slot (bytes)
    const int aswz = (quad ^ ((r16 >> 1) & 3)) * 16;         // swizzled read slot (bytes)

    // one 128-row (8 KB) chunk: exactly 1 gload_lds per wave (8 waves = 128 rows)
    auto stageA = [&](int kt, int sb, int r0) {
        gload_lds16(Q1 + (size_t)(bM + r0 + w * 16 + lrow) * HID + kt * 64 + lq,
                    &ldsA[sb][(r0 + w * 16) * 64]);
    };
    auto stageB = [&](int kt, int sb, int r0) {
        gload_lds16(Q2 + (size_t)(bN + r0 + w * 16 + lrow) * HID + kt * 64 + lq,
                    &ldsB[sb][(r0 + w * 16) * 64]);
    };

    i32x4 acc[8][4] = {};

    // prologue: 2 K-tiles in flight (8 vmem ops per wave)
    stageA(0, 0, 0); stageA(0, 0, 128); stageB(0, 0, 0); stageB(0, 0, 128);
    stageA(1, 1, 0); stageA(1, 1, 128); stageB(1, 1, 0); stageB(1, 1, 128);

    const int NT = HID / 64;   // 8 K-tiles
#pragma unroll
    for (int kt = 0; kt < NT; ++kt) {
        const int rb = kt % 3, sb = (kt + 2) % 3;
        const bool pre = kt < NT - 2;
        if (kt < NT - 1) VMCNT(4); else VMCNT(0);   // counted: kt landed, kt+1 in flight
        BARRIER;                                    // all waves' kt chunks resident

        i32x4 bfr[4], a0, a1;
        // ---- phase 0: B frags + A frags 0,1 | stage A half 0 of kt+2 ----
#pragma unroll
        for (int tn = 0; tn < 4; ++tn)
            bfr[tn] = *(const i32x4*)&ldsB[rb][(wn * 64 + tn * 16 + r16) * 64 + aswz];
        a0 = *(const i32x4*)&ldsA[rb][(wm * 128 + 0 * 16 + r16) * 64 + aswz];
        a1 = *(const i32x4*)&ldsA[rb][(wm * 128 + 1 * 16 + r16) * 64 + aswz];
        if (pre) stageA(kt + 2, sb, 0);
        BARRIER; LGKMCNT0;
        __builtin_amdgcn_s_setprio(1);
#pragma unroll
        for (int tn = 0; tn < 4; ++tn) {
            acc[0][tn] = __builtin_amdgcn_mfma_i32_16x16x64_i8(a0, bfr[tn], acc[0][tn], 0, 0, 0);
            acc[1][tn] = __builtin_amdgcn_mfma_i32_16x16x64_i8(a1, bfr[tn], acc[1][tn], 0, 0, 0);
        }
        __builtin_amdgcn_s_setprio(0);
        BARRIER;
        // ---- phase 1: A frags 2,3 | stage A half 1 ----
        a0 = *(const i32x4*)&ldsA[rb][(wm * 128 + 2 * 16 + r16) * 64 + aswz];
        a1 = *(const i32x4*)&ldsA[rb][(wm * 128 + 3 * 16 + r16) * 64 + aswz];
        if (pre) stageA(kt + 2, sb, 128);
        BARRIER; LGKMCNT0;
        __builtin_amdgcn_s_setprio(1);
#pragma unroll
        for (int tn = 0; tn < 4; ++tn) {
            acc[2][tn] = __builtin_amdgcn_mfma_i32_16x16x64_i8(a0, bfr[tn], acc[2][tn], 0, 0, 0);
            acc[3][tn] = __builtin_amdgcn_mfma_i32_16x16x64_i8(a1, bfr[tn], acc[3][tn], 0, 0, 0);
        }
        __builtin_amdgcn_s_setprio(0);
        BARRIER;
        // ---- phase 2: A frags 4,5 | stage B half 0 ----
        a0 = *(const i32x4*)&ldsA[rb][(wm * 128 + 4 * 16 + r16) * 64 + aswz];
        a1 = *(const i32x4*)&ldsA[rb][(wm * 128 + 5 * 16 + r16) * 64 + aswz];
        if (pre) stageB(kt + 2, sb, 0);
        BARRIER; LGKMCNT0;
        __builtin_amdgcn_s_setprio(1);
#pragma unroll
        for (int tn = 0; tn < 4; ++tn) {
            acc[4][tn] = __builtin_amdgcn_mfma_i32_16x16x64_i8(a0, bfr[tn], acc[4][tn], 0, 0, 0);
            acc[5][tn] = __builtin_amdgcn_mfma_i32_16x16x64_i8(a1, bfr[tn], acc[5][tn], 0, 0, 0);
        }
        __builtin_amdgcn_s_setprio(0);
        BARRIER;
        // ---- phase 3: A frags 6,7 | stage B half 1 ----
        a0 = *(const i32x4*)&ldsA[rb][(wm * 128 + 6 * 16 + r16) * 64 + aswz];
        a1 = *(const i32x4*)&ldsA[rb][(wm * 128 + 7 * 16 + r16) * 64 + aswz];
        if (pre) stageB(kt + 2, sb, 128);
        BARRIER; LGKMCNT0;
        __builtin_amdgcn_s_setprio(1);
#pragma unroll
        for (int tn = 0; tn < 4; ++tn) {
            acc[6][tn] = __builtin_amdgcn_mfma_i32_16x16x64_i8(a0, bfr[tn], acc[6][tn], 0, 0, 0);
            acc[7][tn] = __builtin_amdgcn_mfma_i32_16x16x64_i8(a1, bfr[tn], acc[7][tn], 0, 0, 0);
        }
        __builtin_amdgcn_s_setprio(0);
        BARRIER;
    }

    // ---- epilogue: LDS-first reduction, then 1 global atomic per element ----
    red[tid] = 0.f;
    __syncthreads();

    float cb[4], cs[4] = {0.f, 0.f, 0.f, 0.f};
#pragma unroll
    for (int tn = 0; tn < 4; ++tn)
        cb[tn] = recip[NROWS + bN + wn * 64 + tn * 16 + r16] * (TAU_INV * LOG2E);

#pragma unroll
    for (int tm = 0; tm < 8; ++tm) {
#pragma unroll
        for (int r = 0; r < 4; ++r) {
            int lrow_o = wm * 128 + tm * 16 + quad * 4 + r;    // C/D: row=quad*4+reg
            float ra = recip[bM + lrow_o];
            float rs = 0.f;
#pragma unroll
            for (int tn = 0; tn < 4; ++tn) {
                float e = exp2f((float)acc[tm][tn][r] * ra * cb[tn]);
                rs += e;
                cs[tn] += e;
            }
#pragma unroll
            for (int m = 1; m < 16; m <<= 1) rs += __shfl_xor(rs, m, 64);
            if (r16 == 0) atomicAdd(&red[lrow_o], rs);         // LDS atomic
        }
    }
#pragma unroll
    for (int tn = 0; tn < 4; ++tn) {
        float c = cs[tn];
        c += __shfl_xor(c, 16, 64);
        c += __shfl_xor(c, 32, 64);
        if (quad == 0)
            atomicAdd(&red[256 + wn * 64 + tn * 16 + r16], c); // LDS atomic
    }
    __syncthreads();
    if (tid < 256) atomicAdd(&rowsum[bM + tid], red[tid]);
    else           atomicAdd(&colsum[bN + tid - 256], red[tid]);
}

// ---------------------------------------------------------------------------
// Edge numerators, one wave per node (edges are row-sorted, 8 per node):
// row fragments loaded once; exact int8 dots in float; direct store (no atomic).
// ---------------------------------------------------------------------------
__global__ void edge_kernel(const char* __restrict__ Q1, const char* __restrict__ Q2,
                            const float* __restrict__ recip, const int* __restrict__ pos,
                            float* __restrict__ smp, float* __restrict__ ssc, int E)
{
    int row = blockIdx.x * (blockDim.x >> 6) + (threadIdx.x >> 6);
    int lane = threadIdx.x & 63;
    if (row >= NROWS) return;
    int2 a1 = ((const int2*)(Q1 + (size_t)row * HID))[lane];
    int2 a2 = ((const int2*)(Q2 + (size_t)row * HID))[lane];
    float s1 = 0.f, s2 = 0.f;
    float ir1 = recip[row], ir2 = recip[NROWS + row];
#pragma unroll
    for (int e = 0; e < 8; ++e) {
        int c = pos[E + row * 8 + e];
        int2 b2 = ((const int2*)(Q2 + (size_t)c * HID))[lane];
        int2 b1 = ((const int2*)(Q1 + (size_t)c * HID))[lane];
        float d1 = (float)(dot4i(a1.x, b2.x) + dot4i(a1.y, b2.y));
        float d2 = (float)(dot4i(b1.x, a2.x) + dot4i(b1.y, a2.y));
#pragma unroll
        for (int m = 1; m < 64; m <<= 1) {
            d1 += __shfl_xor(d1, m, 64);
            d2 += __shfl_xor(d2, m, 64);
        }
        if (lane == 0) {
            s1 += __expf(d1 * ir1 * recip[NROWS + c] * TAU_INV);   // S[row,c]
            s2 += __expf(d2 * recip[c] * ir2 * TAU_INV);           // S[c,row]
        }
    }
    if (lane == 0) { smp[row] = s1; ssc[row] = s2; }
}

// Single-block finalize (1024 threads): loss = mean over rows -> out[0].
__global__ void finalize(const float* __restrict__ rowsum, const float* __restrict__ colsum,
                         const float* __restrict__ smp, const float* __restrict__ ssc,
                         float* __restrict__ out, int n)
{
    float contrib = 0.f;
    for (int i = threadIdx.x; i < n; i += blockDim.x) {
        float t = (smp[i] / rowsum[i]) * (ssc[i] / colsum[i]);
        contrib += -0.5f * logf(t) / (float)n;
    }
#pragma unroll
    for (int m = 1; m < 64; m <<= 1) contrib += __shfl_xor(contrib, m, 64);
    __shared__ float wsum[16];
    int w = threadIdx.x >> 6, lane = threadIdx.x & 63;
    if (lane == 0) wsum[w] = contrib;
    __syncthreads();
    if (threadIdx.x == 0) {
        float s = 0.f;
#pragma unroll
        for (int i = 0; i < 16; ++i) s += wsum[i];
        out[0] = s;
    }
}

extern "C" void kernel_launch(void* const* d_in, const int* in_sizes, int n_in,
                              void* d_out, int out_size, void* d_ws, size_t ws_size,
                              hipStream_t stream)
{
    const float* z_mp = (const float*)d_in[0];
    const float* z_sc = (const float*)d_in[1];
    const float* W1f  = (const float*)d_in[2];
    const float* b1   = (const float*)d_in[3];
    const float* W2f  = (const float*)d_in[4];
    const float* b2   = (const float*)d_in[5];
    const int*   pos  = (const int*)d_in[6];
    const int E = in_sizes[6] / 2;
    const int ZN = NROWS * HID;       // 4M elems
    const int WN = HID * HID;         // 256K elems

    // workspace layout (~34 MB):
    //   [0,16MB)   : Zb_mp, Zb_sc (bf16) -> dead after proj1 -> reused as P1,P2
    //   [16,32MB)  : H1,H2 (bf16) -> dead after proj2 -> reused as Q (int8, 8MB)
    //   [32MB,..)  : Wb1, Wb2, rowsum, colsum, recip(64KB), smp, ssc
    char* ws = (char*)d_ws;
    short* Zb1 = (short*)ws;
    short* Zb2 = Zb1 + ZN;
    short* P1  = Zb1;                 // alias: Zb dead after proj1
    short* P2  = Zb2;
    short* H1  = (short*)(ws + (size_t)16 * 1024 * 1024);
    short* H2  = H1 + ZN;
    char*  Q   = (char*)H1;           // alias: H dead after proj2; 2*NROWS rows
    char*  Q1  = Q;
    char*  Q2  = Q + (size_t)NROWS * HID;
    short* Wb1 = (short*)(ws + (size_t)32 * 1024 * 1024);
    short* Wb2 = Wb1 + WN;
    float* rowsum = (float*)(Wb2 + WN);
    float* colsum = rowsum + NROWS;
    float* recip  = colsum + NROWS;   // 2*NROWS floats
    float* smp    = recip + 2 * NROWS;
    float* ssc    = smp + NROWS;

    dim3 blk(256);
    // fp32 -> bf16 conversions + rowsum/colsum zeroing (single launch)
    convert_all<<<dim3((2 * ZN + 2 * WN) / 1024 + 16), blk, 0, stream>>>(
        z_mp, z_sc, W1f, W2f, Zb1, Zb2, Wb1, Wb2, rowsum);
    // H = elu(Z @ W1^T + b1) for both inputs (grid.z); 64x128 tiles, 1024 blocks
    gemm_proj<<<dim3(128, 4, 2), blk, 0, stream>>>(Zb1, Zb2, Wb1, b1, H1, H2, 1);
    // P = H @ W2^T + b2   (P overwrites Zb region — Zb dead now)
    gemm_proj<<<dim3(128, 4, 2), blk, 0, stream>>>(H1, H2, Wb2, b2, P1, P2, 0);
    // normalize + int8 quantize both P1,P2 (2*NROWS contiguous rows) -> Q, recip
    normalize_quant<<<dim3((2 * NROWS) / 4), blk, 0, stream>>>(P1, Q, recip, 2 * NROWS);
    // rowsum/colsum via i8 MFMA, 256x256 tiles, 8-phase barrier-pair pipeline
    gemm_sim<<<dim3(32, 32), dim3(512), 0, stream>>>(Q1, Q2, recip, rowsum, colsum);
    // per-edge numerators, one wave per node, direct store
    edge_kernel<<<dim3(NROWS / 4), blk, 0, stream>>>(Q1, Q2, recip, pos, smp, ssc, E);
    // single-block reduce straight into d_out
    finalize<<<dim3(1), dim3(1024), 0, stream>>>(rowsum, colsum, smp, ssc, (float*)d_out, NROWS);
}

// Round 9
// 216.391 us; speedup vs baseline: 1.1512x; 1.0159x over previous
//
#include <hip/hip_runtime.h>

typedef __attribute__((ext_vector_type(8))) short s16x8;   // 8 bf16
typedef __attribute__((ext_vector_type(4))) float f32x4;
typedef __attribute__((ext_vector_type(4))) int   i32x4;

#define HID 512
#define NROWS 8192
#define TAU_INV 1.25f
#define LOG2E 1.4426950408889634f

// counted waits + raw barrier (T3/T4). memory clobber: LDS/VMEM may not cross.
#define VMCNT(n)  asm volatile("s_waitcnt vmcnt(" #n ")" ::: "memory")
#define LGKMCNT0  asm volatile("s_waitcnt lgkmcnt(0)" ::: "memory")
#define BARRIER   asm volatile("s_barrier" ::: "memory")

__device__ __forceinline__ float bf2f(short s) {
    union { unsigned u; float f; } v;
    v.u = ((unsigned)(unsigned short)s) << 16;
    return v.f;
}
__device__ __forceinline__ short f2bf(float f) {
    unsigned u = __float_as_uint(f);
    u += 0x7fffu + ((u >> 16) & 1u);   // round-to-nearest-even
    return (short)(u >> 16);
}

__device__ __forceinline__ void gload_lds16(const void* g, void* l) {
    __builtin_amdgcn_global_load_lds(
        (const __attribute__((address_space(1))) unsigned int*)g,
        (__attribute__((address_space(3))) unsigned int*)l, 16, 0, 0);
}

__device__ __forceinline__ int dot4i(int a, int b) {
    int s = 0;
#pragma unroll
    for (int i = 0; i < 4; ++i)
        s += (int)(signed char)(a >> (8 * i)) * (int)(signed char)(b >> (8 * i));
    return s;
}

// ---------------------------------------------------------------------------
// Fused fp32->bf16 convert for z_mp, z_sc, W1, W2 + zeroing of rowsum/colsum
// (tail blocks), all in one launch.  (R1-verified)
// ---------------------------------------------------------------------------
__global__ void convert_all(const float* __restrict__ z1, const float* __restrict__ z2,
                            const float* __restrict__ w1, const float* __restrict__ w2,
                            short* __restrict__ Zb1, short* __restrict__ Zb2,
                            short* __restrict__ Wb1, short* __restrict__ Wb2,
                            float* __restrict__ zsum)
{
    const int ZN = NROWS * HID, WN = HID * HID;
    const int NCONV = (2 * ZN + 2 * WN) / 1024;   // conversion blocks
    if ((int)blockIdx.x >= NCONV) {               // tail: zero rowsum+colsum
        int zi = ((int)blockIdx.x - NCONV) * 1024 + threadIdx.x * 4;
        if (zi < 2 * NROWS)
            *(float4*)(zsum + zi) = make_float4(0.f, 0.f, 0.f, 0.f);
        return;
    }
    long i = (long)(blockIdx.x * blockDim.x + threadIdx.x) * 4;
    const float* src;
    short* dst;
    long off;
    if (i < ZN)                { src = z1; dst = Zb1; off = i; }
    else if (i < 2L * ZN)      { src = z2; dst = Zb2; off = i - ZN; }
    else if (i < 2L * ZN + WN) { src = w1; dst = Wb1; off = i - 2L * ZN; }
    else                       { src = w2; dst = Wb2; off = i - 2L * ZN - WN; }
    float4 v = *(const float4*)(src + off);
    short4 o;
    o.x = f2bf(v.x); o.y = f2bf(v.y); o.z = f2bf(v.z); o.w = f2bf(v.w);
    *(short4*)(dst + off) = o;
}

// ---------------------------------------------------------------------------
// bf16 NT GEMM, 64x128 tile — R8-pattern port (T3+T4+T5): 3 LDS buffers
// (36 KB -> still 4 blocks/CU), counted vmcnt(3) with 2 K-tiles in flight
// (never drained mid-loop), one phase-pair per K-tile:
//   {ds_read frags -> stage kt+2 -> s_barrier -> lgkmcnt(0)
//    -> setprio(1) 8 MFMA setprio(0) -> s_barrier}
// Differs from the failed R2 attempt exactly by the barrier PAIRS (wave
// role-split) and the absence of sched_barrier(0) — the two factors R8
// isolated. Hazards: RAW: kt's 3 loads are each wave's oldest -> VMCNT(3)
// + top barrier (all waves waited) before any ds_read of buffer rb.
// WAR: buffer (kt+2)%3 was last ds_read in kt-1, whose lgkmcnt(0) preceded
// kt-1's closing barrier < kt's top barrier < stage issue.
// ---------------------------------------------------------------------------
__global__ __launch_bounds__(256, 4)
void gemm_proj(const short* __restrict__ A0, const short* __restrict__ A1,
               const short* __restrict__ B, const float* __restrict__ bias,
               short* __restrict__ C0, short* __restrict__ C1, int do_elu)
{
    __shared__ short ldsA[3][64 * 32];    // 3 x 4 KB
    __shared__ short ldsB[3][128 * 32];   // 3 x 8 KB
    const short* A = blockIdx.z ? A1 : A0;
    short* C = blockIdx.z ? C1 : C0;
    const int tid = threadIdx.x;
    const int w = tid >> 6, lane = tid & 63;
    const int wm = w & 1, wn = w >> 1;
    const int quad = lane >> 4, r16 = lane & 15;
    const int bM = blockIdx.x * 64, bN = blockIdx.y * 128;
    const int lrow = lane >> 2;
    const int lq   = ((lane & 3) ^ ((lane >> 3) & 3)) * 8;   // swizzled src slot (shorts)
    const int aswz = (quad ^ ((r16 >> 1) & 3)) * 8;          // swizzled read slot (shorts)

    auto stage = [&](int kt, int sb) {    // 3 gload_lds per wave (1 A + 2 B)
        const int k0 = kt * 32;
        {   int r0 = w * 16;
            gload_lds16(A + (size_t)(bM + r0 + lrow) * HID + k0 + lq, &ldsA[sb][r0 * 32]);
        }
#pragma unroll
        for (int i = 0; i < 2; ++i) {
            int r0 = (w * 2 + i) * 16;
            gload_lds16(B + (size_t)(bN + r0 + lrow) * HID + k0 + lq, &ldsB[sb][r0 * 32]);
        }
    };

    f32x4 acc[2][4] = {};

    stage(0, 0);
    stage(1, 1);                          // 2 K-tiles (6 loads) in flight

    const int NT = HID / 32;              // 16 K-tiles
#pragma unroll
    for (int kt = 0; kt < NT; ++kt) {
        const int rb = kt % 3, sb = (kt + 2) % 3;
        if (kt < NT - 1) VMCNT(3); else VMCNT(0);   // counted: kt landed, kt+1 in flight
        BARRIER;
        s16x8 af[2], bfr[4];
#pragma unroll
        for (int t = 0; t < 2; ++t)
            af[t]  = *(const s16x8*)&ldsA[rb][(wm * 32 + t * 16 + r16) * 32 + aswz];
#pragma unroll
        for (int t = 0; t < 4; ++t)
            bfr[t] = *(const s16x8*)&ldsB[rb][(wn * 64 + t * 16 + r16) * 32 + aswz];
        if (kt < NT - 2) stage(kt + 2, sb);
        BARRIER; LGKMCNT0;
        __builtin_amdgcn_s_setprio(1);
#pragma unroll
        for (int tm = 0; tm < 2; ++tm)
#pragma unroll
            for (int tn = 0; tn < 4; ++tn)
                acc[tm][tn] = __builtin_amdgcn_mfma_f32_16x16x32_bf16(
                    af[tm], bfr[tn], acc[tm][tn], 0, 0, 0);
        __builtin_amdgcn_s_setprio(0);
        BARRIER;
    }

#pragma unroll
    for (int tn = 0; tn < 4; ++tn) {
        int gcol = bN + wn * 64 + tn * 16 + r16;
        float bv = bias[gcol];
#pragma unroll
        for (int tm = 0; tm < 2; ++tm) {
#pragma unroll
            for (int r = 0; r < 4; ++r) {
                int grow = bM + wm * 32 + tm * 16 + quad * 4 + r;  // C/D: row=(lane>>4)*4+reg
                float v = acc[tm][tn][r] + bv;
                if (do_elu) v = v > 0.f ? v : __expf(v) - 1.f;
                C[(size_t)grow * HID + gcol] = f2bf(v);
            }
        }
    }
}

// ---------------------------------------------------------------------------
// normalize + int8 row-quantize: q = round(n * 127/max|n_row|), one wave/row.
// recip[row] = max|n_row|/127, so dot_real = i32acc * recip[r] * recip[c].
// ---------------------------------------------------------------------------
__global__ void normalize_quant(const short* __restrict__ P, char* __restrict__ Q,
                                float* __restrict__ recip, int nrows)
{
    int gt = blockIdx.x * blockDim.x + threadIdx.x;
    int row = gt >> 6, lane = gt & 63;
    if (row >= nrows) return;
    const short* p = P + (size_t)row * HID + lane * 8;
    s16x8 v = *(const s16x8*)p;
    float f[8], ss = 0.f, am = 0.f;
#pragma unroll
    for (int i = 0; i < 8; ++i) {
        f[i] = bf2f(v[i]);
        ss += f[i] * f[i];
        am = fmaxf(am, fabsf(f[i]));
    }
#pragma unroll
    for (int m = 1; m < 64; m <<= 1) {
        ss += __shfl_xor(ss, m, 64);
        am = fmaxf(am, __shfl_xor(am, m, 64));
    }
    float inv = rsqrtf(ss);
    float maxn = am * inv;             // max |n_i| over the row
    float s = 127.f / maxn;
    int lo = 0, hi = 0;
#pragma unroll
    for (int i = 0; i < 4; ++i) {
        int q0 = (int)lrintf(f[i] * inv * s);
        int q1 = (int)lrintf(f[i + 4] * inv * s);
        lo |= (q0 & 255) << (8 * i);
        hi |= (q1 & 255) << (8 * i);
    }
    ((int2*)(Q + (size_t)row * HID))[lane] = make_int2(lo, hi);
    if (lane == 0) recip[row] = maxn * (1.f / 127.f);
}

// ---------------------------------------------------------------------------
// int8 similarity — R8's verified 8-phase template, phases COARSENED to the
// reference proportion (16 MFMA per phase): 2 phases per K-tile, 5 barriers
// per kt (was 9). 256x256 tile, 8 waves, BK=64, 3 LDS buffers, counted
// vmcnt(4) (2 K-tiles in flight, never drained mid-loop). Hazard proof
// unchanged from R8 (stages issued after kt's top barrier > kt-1's closing
// barrier; per-phase lgkmcnt(0) precedes each closing barrier). Epilogue:
// R8's LDS-first reduction (WRITE_SIZE 20.5 -> 2 MB measured).
// ---------------------------------------------------------------------------
__global__ __launch_bounds__(512, 1)
void gemm_sim(const char* __restrict__ Q1, const char* __restrict__ Q2,
              const float* __restrict__ recip,
              float* __restrict__ rowsum, float* __restrict__ colsum)
{
    __shared__ char  ldsA[3][256 * 64];   // 3 x 16 KB
    __shared__ char  ldsB[3][256 * 64];   // 3 x 16 KB
    __shared__ float red[512];            // 256 row + 256 col partials
    const int tid = threadIdx.x;
    const int w = tid >> 6, lane = tid & 63;
    const int wm = w >> 2, wn = w & 3;           // 2x4 wave grid -> 128x64 C per wave
    const int quad = lane >> 4, r16 = lane & 15;
    const int bM = blockIdx.x * 256, bN = blockIdx.y * 256;
    const int lrow = lane >> 2;
    const int lq   = ((lane & 3) ^ ((lane >> 3) & 3)) * 16;  // swizzled src slot (bytes)
    const int aswz = (quad ^ ((r16 >> 1) & 3)) * 16;         // swizzled read slot (bytes)

    // one 128-row (8 KB) chunk: exactly 1 gload_lds per wave (8 waves = 128 rows)
    auto stageA = [&](int kt, int sb, int r0) {
        gload_lds16(Q1 + (size_t)(bM + r0 + w * 16 + lrow) * HID + kt * 64 + lq,
                    &ldsA[sb][(r0 + w * 16) * 64]);
    };
    auto stageB = [&](int kt, int sb, int r0) {
        gload_lds16(Q2 + (size_t)(bN + r0 + w * 16 + lrow) * HID + kt * 64 + lq,
                    &ldsB[sb][(r0 + w * 16) * 64]);
    };

    i32x4 acc[8][4] = {};

    // prologue: 2 K-tiles in flight (8 vmem ops per wave)
    stageA(0, 0, 0); stageA(0, 0, 128); stageB(0, 0, 0); stageB(0, 0, 128);
    stageA(1, 1, 0); stageA(1, 1, 128); stageB(1, 1, 0); stageB(1, 1, 128);

    const int NT = HID / 64;   // 8 K-tiles
#pragma unroll
    for (int kt = 0; kt < NT; ++kt) {
        const int rb = kt % 3, sb = (kt + 2) % 3;
        const bool pre = kt < NT - 2;
        if (kt < NT - 1) VMCNT(4); else VMCNT(0);   // counted: kt landed, kt+1 in flight
        BARRIER;                                    // all waves' kt chunks resident

        i32x4 bfr[4], a0, a1, a2, a3;
        // ---- phase A: B frags + A frags 0-3 | stage A(kt+2) both halves ----
#pragma unroll
        for (int tn = 0; tn < 4; ++tn)
            bfr[tn] = *(const i32x4*)&ldsB[rb][(wn * 64 + tn * 16 + r16) * 64 + aswz];
        a0 = *(const i32x4*)&ldsA[rb][(wm * 128 + 0 * 16 + r16) * 64 + aswz];
        a1 = *(const i32x4*)&ldsA[rb][(wm * 128 + 1 * 16 + r16) * 64 + aswz];
        a2 = *(const i32x4*)&ldsA[rb][(wm * 128 + 2 * 16 + r16) * 64 + aswz];
        a3 = *(const i32x4*)&ldsA[rb][(wm * 128 + 3 * 16 + r16) * 64 + aswz];
        if (pre) { stageA(kt + 2, sb, 0); stageA(kt + 2, sb, 128); }
        BARRIER; LGKMCNT0;
        __builtin_amdgcn_s_setprio(1);
#pragma unroll
        for (int tn = 0; tn < 4; ++tn) {
            acc[0][tn] = __builtin_amdgcn_mfma_i32_16x16x64_i8(a0, bfr[tn], acc[0][tn], 0, 0, 0);
            acc[1][tn] = __builtin_amdgcn_mfma_i32_16x16x64_i8(a1, bfr[tn], acc[1][tn], 0, 0, 0);
            acc[2][tn] = __builtin_amdgcn_mfma_i32_16x16x64_i8(a2, bfr[tn], acc[2][tn], 0, 0, 0);
            acc[3][tn] = __builtin_amdgcn_mfma_i32_16x16x64_i8(a3, bfr[tn], acc[3][tn], 0, 0, 0);
        }
        __builtin_amdgcn_s_setprio(0);
        BARRIER;
        // ---- phase B: A frags 4-7 | stage B(kt+2) both halves ----
        a0 = *(const i32x4*)&ldsA[rb][(wm * 128 + 4 * 16 + r16) * 64 + aswz];
        a1 = *(const i32x4*)&ldsA[rb][(wm * 128 + 5 * 16 + r16) * 64 + aswz];
        a2 = *(const i32x4*)&ldsA[rb][(wm * 128 + 6 * 16 + r16) * 64 + aswz];
        a3 = *(const i32x4*)&ldsA[rb][(wm * 128 + 7 * 16 + r16) * 64 + aswz];
        if (pre) { stageB(kt + 2, sb, 0); stageB(kt + 2, sb, 128); }
        BARRIER; LGKMCNT0;
        __builtin_amdgcn_s_setprio(1);
#pragma unroll
        for (int tn = 0; tn < 4; ++tn) {
            acc[4][tn] = __builtin_amdgcn_mfma_i32_16x16x64_i8(a0, bfr[tn], acc[4][tn], 0, 0, 0);
            acc[5][tn] = __builtin_amdgcn_mfma_i32_16x16x64_i8(a1, bfr[tn], acc[5][tn], 0, 0, 0);
            acc[6][tn] = __builtin_amdgcn_mfma_i32_16x16x64_i8(a2, bfr[tn], acc[6][tn], 0, 0, 0);
            acc[7][tn] = __builtin_amdgcn_mfma_i32_16x16x64_i8(a3, bfr[tn], acc[7][tn], 0, 0, 0);
        }
        __builtin_amdgcn_s_setprio(0);
        BARRIER;
    }

    // ---- epilogue: LDS-first reduction, then 1 global atomic per element ----
    red[tid] = 0.f;
    __syncthreads();

    float cb[4], cs[4] = {0.f, 0.f, 0.f, 0.f};
#pragma unroll
    for (int tn = 0; tn < 4; ++tn)
        cb[tn] = recip[NROWS + bN + wn * 64 + tn * 16 + r16] * (TAU_INV * LOG2E);

#pragma unroll
    for (int tm = 0; tm < 8; ++tm) {
#pragma unroll
        for (int r = 0; r < 4; ++r) {
            int lrow_o = wm * 128 + tm * 16 + quad * 4 + r;    // C/D: row=quad*4+reg
            float ra = recip[bM + lrow_o];
            float rs = 0.f;
#pragma unroll
            for (int tn = 0; tn < 4; ++tn) {
                float e = exp2f((float)acc[tm][tn][r] * ra * cb[tn]);
                rs += e;
                cs[tn] += e;
            }
#pragma unroll
            for (int m = 1; m < 16; m <<= 1) rs += __shfl_xor(rs, m, 64);
            if (r16 == 0) atomicAdd(&red[lrow_o], rs);         // LDS atomic
        }
    }
#pragma unroll
    for (int tn = 0; tn < 4; ++tn) {
        float c = cs[tn];
        c += __shfl_xor(c, 16, 64);
        c += __shfl_xor(c, 32, 64);
        if (quad == 0)
            atomicAdd(&red[256 + wn * 64 + tn * 16 + r16], c); // LDS atomic
    }
    __syncthreads();
    if (tid < 256) atomicAdd(&rowsum[bM + tid], red[tid]);
    else           atomicAdd(&colsum[bN + tid - 256], red[tid]);
}

// ---------------------------------------------------------------------------
// Edge numerators, one wave per node (edges are row-sorted, 8 per node):
// row fragments loaded once; exact int8 dots in float; direct store (no atomic).
// ---------------------------------------------------------------------------
__global__ void edge_kernel(const char* __restrict__ Q1, const char* __restrict__ Q2,
                            const float* __restrict__ recip, const int* __restrict__ pos,
                            float* __restrict__ smp, float* __restrict__ ssc, int E)
{
    int row = blockIdx.x * (blockDim.x >> 6) + (threadIdx.x >> 6);
    int lane = threadIdx.x & 63;
    if (row >= NROWS) return;
    int2 a1 = ((const int2*)(Q1 + (size_t)row * HID))[lane];
    int2 a2 = ((const int2*)(Q2 + (size_t)row * HID))[lane];
    float s1 = 0.f, s2 = 0.f;
    float ir1 = recip[row], ir2 = recip[NROWS + row];
#pragma unroll
    for (int e = 0; e < 8; ++e) {
        int c = pos[E + row * 8 + e];
        int2 b2 = ((const int2*)(Q2 + (size_t)c * HID))[lane];
        int2 b1 = ((const int2*)(Q1 + (size_t)c * HID))[lane];
        float d1 = (float)(dot4i(a1.x, b2.x) + dot4i(a1.y, b2.y));
        float d2 = (float)(dot4i(b1.x, a2.x) + dot4i(b1.y, a2.y));
#pragma unroll
        for (int m = 1; m < 64; m <<= 1) {
            d1 += __shfl_xor(d1, m, 64);
            d2 += __shfl_xor(d2, m, 64);
        }
        if (lane == 0) {
            s1 += __expf(d1 * ir1 * recip[NROWS + c] * TAU_INV);   // S[row,c]
            s2 += __expf(d2 * recip[c] * ir2 * TAU_INV);           // S[c,row]
        }
    }
    if (lane == 0) { smp[row] = s1; ssc[row] = s2; }
}

// Single-block finalize (1024 threads): loss = mean over rows -> out[0].
__global__ void finalize(const float* __restrict__ rowsum, const float* __restrict__ colsum,
                         const float* __restrict__ smp, const float* __restrict__ ssc,
                         float* __restrict__ out, int n)
{
    float contrib = 0.f;
    for (int i = threadIdx.x; i < n; i += blockDim.x) {
        float t = (smp[i] / rowsum[i]) * (ssc[i] / colsum[i]);
        contrib += -0.5f * logf(t) / (float)n;
    }
#pragma unroll
    for (int m = 1; m < 64; m <<= 1) contrib += __shfl_xor(contrib, m, 64);
    __shared__ float wsum[16];
    int w = threadIdx.x >> 6, lane = threadIdx.x & 63;
    if (lane == 0) wsum[w] = contrib;
    __syncthreads();
    if (threadIdx.x == 0) {
        float s = 0.f;
#pragma unroll
        for (int i = 0; i < 16; ++i) s += wsum[i];
        out[0] = s;
    }
}

extern "C" void kernel_launch(void* const* d_in, const int* in_sizes, int n_in,
                              void* d_out, int out_size, void* d_ws, size_t ws_size,
                              hipStream_t stream)
{
    const float* z_mp = (const float*)d_in[0];
    const float* z_sc = (const float*)d_in[1];
    const float* W1f  = (const float*)d_in[2];
    const float* b1   = (const float*)d_in[3];
    const float* W2f  = (const float*)d_in[4];
    const float* b2   = (const float*)d_in[5];
    const int*   pos  = (const int*)d_in[6];
    const int E = in_sizes[6] / 2;
    const int ZN = NROWS * HID;       // 4M elems
    const int WN = HID * HID;         // 256K elems

    // workspace layout (~34 MB):
    //   [0,16MB)   : Zb_mp, Zb_sc (bf16) -> dead after proj1 -> reused as P1,P2
    //   [16,32MB)  : H1,H2 (bf16) -> dead after proj2 -> reused as Q (int8, 8MB)
    //   [32MB,..)  : Wb1, Wb2, rowsum, colsum, recip(64KB), smp, ssc
    char* ws = (char*)d_ws;
    short* Zb1 = (short*)ws;
    short* Zb2 = Zb1 + ZN;
    short* P1  = Zb1;                 // alias: Zb dead after proj1
    short* P2  = Zb2;
    short* H1  = (short*)(ws + (size_t)16 * 1024 * 1024);
    short* H2  = H1 + ZN;
    char*  Q   = (char*)H1;           // alias: H dead after proj2; 2*NROWS rows
    char*  Q1  = Q;
    char*  Q2  = Q + (size_t)NROWS * HID;
    short* Wb1 = (short*)(ws + (size_t)32 * 1024 * 1024);
    short* Wb2 = Wb1 + WN;
    float* rowsum = (float*)(Wb2 + WN);
    float* colsum = rowsum + NROWS;
    float* recip  = colsum + NROWS;   // 2*NROWS floats
    float* smp    = recip + 2 * NROWS;
    float* ssc    = smp + NROWS;

    dim3 blk(256);
    // fp32 -> bf16 conversions + rowsum/colsum zeroing (single launch)
    convert_all<<<dim3((2 * ZN + 2 * WN) / 1024 + 16), blk, 0, stream>>>(
        z_mp, z_sc, W1f, W2f, Zb1, Zb2, Wb1, Wb2, rowsum);
    // H = elu(Z @ W1^T + b1) for both inputs (grid.z); R8-pattern pipeline
    gemm_proj<<<dim3(128, 4, 2), blk, 0, stream>>>(Zb1, Zb2, Wb1, b1, H1, H2, 1);
    // P = H @ W2^T + b2   (P overwrites Zb region — Zb dead now)
    gemm_proj<<<dim3(128, 4, 2), blk, 0, stream>>>(H1, H2, Wb2, b2, P1, P2, 0);
    // normalize + int8 quantize both P1,P2 (2*NROWS contiguous rows) -> Q, recip
    normalize_quant<<<dim3((2 * NROWS) / 4), blk, 0, stream>>>(P1, Q, recip, 2 * NROWS);
    // rowsum/colsum via i8 MFMA, 256x256 tiles, 2-phase barrier-pair pipeline
    gemm_sim<<<dim3(32, 32), dim3(512), 0, stream>>>(Q1, Q2, recip, rowsum, colsum);
    // per-edge numerators, one wave per node, direct store
    edge_kernel<<<dim3(NROWS / 4), blk, 0, stream>>>(Q1, Q2, recip, pos, smp, ssc, E);
    // single-block reduce straight into d_out
    finalize<<<dim3(1), dim3(1024), 0, stream>>>(rowsum, colsum, smp, ssc, (float*)d_out, NROWS);
}